// Round 1
// baseline (48.579 us; speedup 1.0000x reference)
//
#include <hip/hip_runtime.h>

// Causal depthwise Conv1d: x[B,L,C] (f32), weight[C,1,K] (f32), bias[C] (f32)
// y[b,l,c] = bias[c] + sum_{k=0..K-1} w[c,0,k] * x[b, l-(K-1)+k, c], zero-pad left.
// B=8, L=4096, C=1024, K=7. Memory-bound streaming kernel.

constexpr int Lc  = 4096;
constexpr int C4  = 256;   // C / 4 float4 lanes
constexpr int K   = 7;
constexpr int LT  = 32;    // L positions per block (rolling window in registers)

__global__ __launch_bounds__(256) void dwconv_kernel(
    const float4* __restrict__ x, const float* __restrict__ w,
    const float* __restrict__ bias, float4* __restrict__ y) {
  const int c4 = threadIdx.x;          // 0..255  -> channels c4*4 .. c4*4+3
  const int l0 = blockIdx.x * LT;      // L-tile start
  const int b  = blockIdx.y;           // batch
  const int c  = c4 * 4;

  // Per-thread weights for its 4 channels: w[c+j][k]
  float wk[K][4];
#pragma unroll
  for (int k = 0; k < K; ++k) {
#pragma unroll
    for (int j = 0; j < 4; ++j) {
      wk[k][j] = w[(c + j) * K + k];
    }
  }

  float4 bv;
  bv.x = bias[c + 0];
  bv.y = bias[c + 1];
  bv.z = bias[c + 2];
  bv.w = bias[c + 3];

  const float4* xb = x + (size_t)b * Lc * C4 + c4;
  float4*       yb = y + (size_t)b * Lc * C4 + c4;

  // Rolling window: before iteration i, slots (i+0)%K .. (i+K-2)%K hold
  // x[l0+i-6 .. l0+i-1]; we load x[l0+i] into slot (i+K-1)%K.
  float4 win[K];
#pragma unroll
  for (int i = 0; i < K - 1; ++i) {
    const int l = l0 - (K - 1) + i;
    if (l >= 0) {
      win[i] = xb[(size_t)l * C4];
    } else {
      win[i] = make_float4(0.f, 0.f, 0.f, 0.f);
    }
  }

#pragma unroll
  for (int i = 0; i < LT; ++i) {
    const int l = l0 + i;
    win[(i + K - 1) % K] = xb[(size_t)l * C4];
    float4 acc = bv;
#pragma unroll
    for (int k = 0; k < K; ++k) {
      const float4 v = win[(i + k) % K];
      acc.x = fmaf(wk[k][0], v.x, acc.x);
      acc.y = fmaf(wk[k][1], v.y, acc.y);
      acc.z = fmaf(wk[k][2], v.z, acc.z);
      acc.w = fmaf(wk[k][3], v.w, acc.w);
    }
    yb[(size_t)l * C4] = acc;
  }
}

extern "C" void kernel_launch(void* const* d_in, const int* in_sizes, int n_in,
                              void* d_out, int out_size, void* d_ws, size_t ws_size,
                              hipStream_t stream) {
  const float4* x    = (const float4*)d_in[0];   // [B, L, C] f32, viewed as float4
  const float*  w    = (const float*)d_in[1];    // [C, 1, K]
  const float*  bias = (const float*)d_in[2];    // [C]
  float4*       y    = (float4*)d_out;           // [B, L, C] f32

  const int B = 8;
  dim3 grid(Lc / LT, B, 1);   // 128 x 8 = 1024 blocks
  dim3 block(C4, 1, 1);       // 256 threads, one float4-lane per 4 channels
  dwconv_kernel<<<grid, block, 0, stream>>>(x, w, bias, y);
}